// Round 1
// baseline (318.895 us; speedup 1.0000x reference)
//
#include <hip/hip_runtime.h>

#define BN 8192
#define DIM 512
#define TEMP 0.07f
#define NPART 8
#define JT_PER 8
#define NEGINF (-__builtin_inff())

typedef _Float16 half8 __attribute__((ext_vector_type(8)));
typedef float f32x4 __attribute__((ext_vector_type(4)));

// async 16B global->LDS (wave-uniform base + lane*16 on the LDS side)
#define GLOAD16(gp, lp) __builtin_amdgcn_global_load_lds( \
    (__attribute__((address_space(1))) const void*)(gp),  \
    (__attribute__((address_space(3))) void*)(lp), 16, 0, 0)

__device__ __forceinline__ void ins5(float t5[5], float v) {
#pragma unroll
  for (int k = 0; k < 5; k++) {
    float old = t5[k];
    bool gt = v > old;
    t5[k] = gt ? v : old;
    v = gt ? old : v;
  }
}

// ---------- 1. L2-normalize fp32 rows -> fp16 matrix (one wave per row) ----------
__global__ __launch_bounds__(256) void k_normalize(const float* __restrict__ feat,
                                                   _Float16* __restrict__ f16) {
  int gid = blockIdx.x * 256 + threadIdx.x;
  int row = gid >> 6, lane = gid & 63;
  const float4* rp = (const float4*)(feat + (size_t)row * DIM);
  float4 v0 = rp[lane * 2];
  float4 v1 = rp[lane * 2 + 1];
  float ss = v0.x * v0.x + v0.y * v0.y + v0.z * v0.z + v0.w * v0.w +
             v1.x * v1.x + v1.y * v1.y + v1.z * v1.z + v1.w * v1.w;
#pragma unroll
  for (int m = 1; m < 64; m <<= 1) ss += __shfl_xor(ss, m, 64);
  float r = 1.0f / fmaxf(sqrtf(ss), 1e-12f);
  half8 o;
  o[0] = (_Float16)(v0.x * r); o[1] = (_Float16)(v0.y * r);
  o[2] = (_Float16)(v0.z * r); o[3] = (_Float16)(v0.w * r);
  o[4] = (_Float16)(v1.x * r); o[5] = (_Float16)(v1.y * r);
  o[6] = (_Float16)(v1.z * r); o[7] = (_Float16)(v1.w * r);
  ((half8*)(f16 + (size_t)row * DIM))[lane] = o;
}

// ---------- 2. positive-pair stats (one wave per row): m, s(online LSE), pos_sum, cnt ----------
__global__ __launch_bounds__(256) void k_posstats(const _Float16* __restrict__ f16,
                                                  const int* __restrict__ idx,
                                                  float4* __restrict__ stats) {
  int gid = blockIdx.x * 256 + threadIdx.x;
  int row = gid >> 6, lane = gid & 63;
  int my = idx[row];
  half8 ha = ((const half8*)(f16 + (size_t)row * DIM))[lane];
  float a0 = ha[0], a1 = ha[1], a2 = ha[2], a3 = ha[3];
  float a4 = ha[4], a5 = ha[5], a6 = ha[6], a7 = ha[7];
  float m = NEGINF, s = 0.f, psum = 0.f, cnt = 0.f;
  for (int jb = 0; jb < BN; jb += 64) {
    bool match = (idx[jb + lane] == my);
    unsigned long long mask = __ballot(match);
    unsigned d = (unsigned)(row - jb);
    if (d < 64u) mask &= ~(1ull << d);  // exclude self
    while (mask) {
      int bit = __ffsll(mask) - 1;
      mask &= mask - 1;
      half8 hb = ((const half8*)(f16 + (size_t)(jb + bit) * DIM))[lane];
      float dd = a0 * (float)hb[0] + a1 * (float)hb[1] + a2 * (float)hb[2] + a3 * (float)hb[3] +
                 a4 * (float)hb[4] + a5 * (float)hb[5] + a6 * (float)hb[6] + a7 * (float)hb[7];
#pragma unroll
      for (int mm = 1; mm < 64; mm <<= 1) dd += __shfl_xor(dd, mm, 64);
      float nm = fmaxf(m, dd);
      s = s * expf((m - nm) / TEMP) + expf((dd - nm) / TEMP);  // m=-inf -> 0*0, safe
      m = nm;
      psum += dd;
      cnt += 1.f;
    }
  }
  if (lane == 0) stats[row] = make_float4(m, s, psum, cnt);
}

// ---------- 3. fused fp16-MFMA sim GEMM + per-row top-5 (m97 structure) ----------
// grid: 512 blocks = 64 i-tiles x 8 j-partitions; block = 256 thr (2x2 waves of 64x64)
__global__ __launch_bounds__(256, 3) void k_gemm_top5(const _Float16* __restrict__ f16,
                                                      float* __restrict__ toppart) {
  __shared__ float Csm[64 * 129];          // 33,024 B; epilogue C half-tile, stride 129 (bank = row+col)
  _Float16* Asm = (_Float16*)Csm;          // staging alias: [128][64] fp16 = 16 KB
  _Float16* Bsm = Asm + 128 * 64;          // next 16 KB (total 32 KB <= 33 KB)

  int t = threadIdx.x;
  int w = t >> 6, lane = t & 63;
  int wr = w >> 1, wc = w & 1;
  int l15 = lane & 15, l4 = lane >> 4;
  int bi = blockIdx.x >> 3;
  int part = blockIdx.x & 7;

  float t5a[5], t5b[5];
#pragma unroll
  for (int k = 0; k < 5; k++) { t5a[k] = NEGINF; t5b[k] = NEGINF; }

  int srow = t & 63;   // scan row within 64-row phase (lane==srow within wave -> conflict-free)
  int sq = t >> 6;     // column quarter (32 cols)
  int growA = bi * 128 + srow;
  int growB = growA + 64;

  int crow = t >> 3;   // staging: 32 rows per pass
  int cko = t & 7;     // k-octet

  for (int jt = 0; jt < JT_PER; jt++) {
    int jbase = (part * JT_PER + jt) * 128;
    f32x4 acc[4][4] = {};

    for (int kc = 0; kc < 8; kc++) {
      int k0 = kc * 64;
      __syncthreads();  // prev consumers (MFMA reads / epilogue scan) done before restage
#pragma unroll
      for (int p = 0; p < 4; p++) {
        int row = p * 32 + crow;
        const _Float16* sA = f16 + (size_t)(bi * 128 + row) * DIM + k0 + cko * 8;
        const _Float16* sB = f16 + (size_t)(jbase + row) * DIM + k0 + cko * 8;
        GLOAD16(sA, Asm + (row * 8 + cko) * 8);
        GLOAD16(sB, Bsm + (row * 8 + cko) * 8);
      }
      __syncthreads();  // vmcnt drained by barrier
#pragma unroll
      for (int s = 0; s < 2; s++) {
        half8 af[4], bf[4];
#pragma unroll
        for (int ti = 0; ti < 4; ti++)
          af[ti] = *(const half8*)(Asm + (wr * 64 + ti * 16 + l15) * 64 + s * 32 + l4 * 8);
#pragma unroll
        for (int tj = 0; tj < 4; tj++)
          bf[tj] = *(const half8*)(Bsm + (wc * 64 + tj * 16 + l15) * 64 + s * 32 + l4 * 8);
#pragma unroll
        for (int ti = 0; ti < 4; ti++)
#pragma unroll
          for (int tj = 0; tj < 4; tj++)
            acc[ti][tj] = __builtin_amdgcn_mfma_f32_16x16x32_f16(af[ti], bf[tj], acc[ti][tj], 0, 0, 0);
      }
    }

    // epilogue: two 64-row phases so LDS stays at 33 KB (3 blocks/CU)
    auto dump = [&]() {
#pragma unroll
      for (int ti = 0; ti < 4; ti++) {
        int r0 = ti * 16 + l4 * 4;
#pragma unroll
        for (int tj = 0; tj < 4; tj++) {
          int c = wc * 64 + tj * 16 + l15;
#pragma unroll
          for (int reg = 0; reg < 4; reg++)
            Csm[(r0 + reg) * 129 + c] = acc[ti][tj][reg];
        }
      }
    };
    auto scan = [&](float (&t5)[5], int grow) {
      const float* rowp = Csm + srow * 129 + sq * 32;
      int gc0 = jbase + sq * 32;
#pragma unroll
      for (int it = 0; it < 8; it++) {
        float v0 = rowp[it * 4 + 0], v1 = rowp[it * 4 + 1];
        float v2 = rowp[it * 4 + 2], v3 = rowp[it * 4 + 3];
        float mx = fmaxf(fmaxf(v0, v1), fmaxf(v2, v3));
        if (mx > t5[4]) {  // rare after warm-up (~5/t per row per tile)
          int gc = gc0 + it * 4;
          if (v0 > t5[4] && gc + 0 != grow) ins5(t5, v0);
          if (v1 > t5[4] && gc + 1 != grow) ins5(t5, v1);
          if (v2 > t5[4] && gc + 2 != grow) ins5(t5, v2);
          if (v3 > t5[4] && gc + 3 != grow) ins5(t5, v3);
        }
      }
    };

    __syncthreads();               // all MFMA LDS reads done before C overwrite
    if (wr == 0) dump();           // rows 0..63
    __syncthreads();
    scan(t5a, growA);
    __syncthreads();
    if (wr == 1) dump();           // rows 64..127
    __syncthreads();
    scan(t5b, growB);
  }

  // write partial top-5 lists: toppart[part][global_row][quarter][8]
  {
    float* d1 = toppart + ((size_t)part * BN + (size_t)(bi * 128 + srow)) * 32 + sq * 8;
#pragma unroll
    for (int k = 0; k < 5; k++) d1[k] = t5a[k];
    float* d2 = toppart + ((size_t)part * BN + (size_t)(bi * 128 + 64 + srow)) * 32 + sq * 8;
#pragma unroll
    for (int k = 0; k < 5; k++) d2[k] = t5b[k];
  }
}

// ---------- 4. merge 8 parts x 4 quarters of sorted top-5 lists per row ----------
__global__ __launch_bounds__(256) void k_merge(const float* __restrict__ toppart,
                                               float* __restrict__ merged) {
  int row = blockIdx.x * 256 + threadIdx.x;
  float t5[5];
#pragma unroll
  for (int k = 0; k < 5; k++) t5[k] = NEGINF;
  for (int p = 0; p < NPART; p++) {
    const float* src = toppart + ((size_t)p * BN + row) * 32;
#pragma unroll
    for (int q = 0; q < 4; q++) {
      const float* s5 = src + q * 8;
      for (int k = 0; k < 5; k++) {   // lists sorted desc -> early break
        float v = s5[k];
        if (!(v > t5[4])) break;
        ins5(t5, v);
      }
    }
  }
  float* d = merged + (size_t)row * 8;
#pragma unroll
  for (int k = 0; k < 5; k++) d[k] = t5[k];
}

// ---------- 5. global max + per-row loss + mean (single block) ----------
__global__ __launch_bounds__(256) void k_final(const float* __restrict__ merged,
                                               const float4* __restrict__ stats,
                                               float* __restrict__ out) {
  __shared__ float red[256];
  int t = threadIdx.x;
  float mg = NEGINF;
  for (int r = t; r < BN; r += 256) mg = fmaxf(mg, merged[(size_t)r * 8]);
  red[t] = mg;
  __syncthreads();
  for (int o = 128; o > 0; o >>= 1) {
    if (t < o) red[t] = fmaxf(red[t], red[t + o]);
    __syncthreads();
  }
  float Mg = red[0];
  __syncthreads();
  float sum = 0.f;
  for (int r = t; r < BN; r += 256) {
    const float* m5 = merged + (size_t)r * 8;
    float h = 0.f;
#pragma unroll
    for (int k = 0; k < 5; k++) h += expf((m5[k] - Mg) / TEMP);
    float4 st = stats[r];  // m, s, psum, cnt
    if (st.w > 0.f) sum += logf(st.y + h) - (st.z / st.w) / TEMP;
    // cnt==0 rows contribute 0 (matches reference NaN-masked semantics)
  }
  red[t] = sum;
  __syncthreads();
  for (int o = 128; o > 0; o >>= 1) {
    if (t < o) red[t] += red[t + o];
    __syncthreads();
  }
  if (t == 0) out[0] = red[0] * (1.0f / (float)BN);
}

extern "C" void kernel_launch(void* const* d_in, const int* in_sizes, int n_in,
                              void* d_out, int out_size, void* d_ws, size_t ws_size,
                              hipStream_t stream) {
  const float* feat = (const float*)d_in[0];
  const int* idx = (const int*)d_in[1];
  float* out = (float*)d_out;
  char* ws = (char*)d_ws;

  _Float16* f16 = (_Float16*)ws;                                 // 8 MB
  float* toppart = (float*)(ws + (size_t)8 * 1024 * 1024);       // 8 MB (8x8192x32 f32)
  float* merged = (float*)(ws + (size_t)16 * 1024 * 1024);       // 256 KB
  float4* stats = (float4*)(ws + (size_t)16 * 1024 * 1024 + 262144);  // 128 KB

  k_normalize<<<dim3(BN / 4), dim3(256), 0, stream>>>(feat, f16);
  k_posstats<<<dim3(BN / 4), dim3(256), 0, stream>>>(f16, idx, stats);
  k_gemm_top5<<<dim3((BN / 128) * NPART), dim3(256), 0, stream>>>(f16, toppart);
  k_merge<<<dim3(BN / 256), dim3(256), 0, stream>>>(toppart, merged);
  k_final<<<dim3(1), dim3(256), 0, stream>>>(merged, stats, out);
}

// Round 2
// 247.840 us; speedup vs baseline: 1.2867x; 1.2867x over previous
//
#include <hip/hip_runtime.h>

#define BN 8192
#define DIM 512
#define TEMP 0.07f
#define NPART 16
#define JT_PER 4
#define NEGINF (-__builtin_inff())

typedef _Float16 half8 __attribute__((ext_vector_type(8)));
typedef float f32x4 __attribute__((ext_vector_type(4)));

// async 16B global->LDS (wave-uniform base + lane*16 on the LDS side)
#define GLOAD16(gp, lp) __builtin_amdgcn_global_load_lds( \
    (__attribute__((address_space(1))) const void*)(gp),  \
    (__attribute__((address_space(3))) void*)(lp), 16, 0, 0)

__device__ __forceinline__ void ins5(float t5[5], float v) {
#pragma unroll
  for (int k = 0; k < 5; k++) {
    float old = t5[k];
    bool gt = v > old;
    t5[k] = gt ? v : old;
    v = gt ? old : v;
  }
}

// monotone float<->uint encoding for atomicMax on signed floats
__device__ __forceinline__ unsigned encf(float x) {
  unsigned u = __float_as_uint(x);
  return (u >> 31) ? ~u : (u | 0x80000000u);
}
__device__ __forceinline__ float decf(unsigned e) {
  unsigned u = (e & 0x80000000u) ? (e & 0x7FFFFFFFu) : ~e;
  return __uint_as_float(u);
}

// ---------- 1. L2-normalize fp32 rows -> fp16 matrix (one wave per row) ----------
__global__ __launch_bounds__(256) void k_normalize(const float* __restrict__ feat,
                                                   _Float16* __restrict__ f16,
                                                   unsigned* __restrict__ cells) {
  if (blockIdx.x == 0 && threadIdx.x == 0) {
    cells[0] = encf(NEGINF);        // global-max accumulator (encoded)
    ((float*)cells)[1] = 0.0f;      // loss-sum accumulator
  }
  int gid = blockIdx.x * 256 + threadIdx.x;
  int row = gid >> 6, lane = gid & 63;
  const float4* rp = (const float4*)(feat + (size_t)row * DIM);
  float4 v0 = rp[lane * 2];
  float4 v1 = rp[lane * 2 + 1];
  float ss = v0.x * v0.x + v0.y * v0.y + v0.z * v0.z + v0.w * v0.w +
             v1.x * v1.x + v1.y * v1.y + v1.z * v1.z + v1.w * v1.w;
#pragma unroll
  for (int m = 1; m < 64; m <<= 1) ss += __shfl_xor(ss, m, 64);
  float r = 1.0f / fmaxf(sqrtf(ss), 1e-12f);
  half8 o;
  o[0] = (_Float16)(v0.x * r); o[1] = (_Float16)(v0.y * r);
  o[2] = (_Float16)(v0.z * r); o[3] = (_Float16)(v0.w * r);
  o[4] = (_Float16)(v1.x * r); o[5] = (_Float16)(v1.y * r);
  o[6] = (_Float16)(v1.z * r); o[7] = (_Float16)(v1.w * r);
  ((half8*)(f16 + (size_t)row * DIM))[lane] = o;
}

// ---------- 2. positive-pair stats (one wave per row): m, s(online LSE), pos_sum, cnt ----------
__global__ __launch_bounds__(256) void k_posstats(const _Float16* __restrict__ f16,
                                                  const int* __restrict__ idx,
                                                  float4* __restrict__ stats) {
  int gid = blockIdx.x * 256 + threadIdx.x;
  int row = gid >> 6, lane = gid & 63;
  int my = idx[row];
  half8 ha = ((const half8*)(f16 + (size_t)row * DIM))[lane];
  float a0 = ha[0], a1 = ha[1], a2 = ha[2], a3 = ha[3];
  float a4 = ha[4], a5 = ha[5], a6 = ha[6], a7 = ha[7];
  float m = NEGINF, s = 0.f, psum = 0.f, cnt = 0.f;
  const int4* idx4 = (const int4*)idx;
  for (int jb = 0; jb < BN; jb += 256) {
    int4 v = idx4[(jb >> 2) + lane];   // lane covers ints jb+4*lane .. +3
    unsigned long long ms[4];
    ms[0] = __ballot(v.x == my);
    ms[1] = __ballot(v.y == my);
    ms[2] = __ballot(v.z == my);
    ms[3] = __ballot(v.w == my);
    unsigned d = (unsigned)(row - jb);
    if (d < 256u) ms[d & 3] &= ~(1ull << (d >> 2));  // exclude self
#pragma unroll
    for (int c = 0; c < 4; c++) {
      unsigned long long mask = ms[c];
      while (mask) {
        int bit = __ffsll(mask) - 1;
        mask &= mask - 1;
        int j = jb + (bit << 2) + c;
        half8 hb = ((const half8*)(f16 + (size_t)j * DIM))[lane];
        float dd = a0 * (float)hb[0] + a1 * (float)hb[1] + a2 * (float)hb[2] + a3 * (float)hb[3] +
                   a4 * (float)hb[4] + a5 * (float)hb[5] + a6 * (float)hb[6] + a7 * (float)hb[7];
#pragma unroll
        for (int mm = 1; mm < 64; mm <<= 1) dd += __shfl_xor(dd, mm, 64);
        float nm = fmaxf(m, dd);
        s = s * expf((m - nm) / TEMP) + expf((dd - nm) / TEMP);  // m=-inf -> 0*0, safe
        m = nm;
        psum += dd;
        cnt += 1.f;
      }
    }
  }
  if (lane == 0) stats[row] = make_float4(m, s, psum, cnt);
}

// ---------- 3. fused fp16-MFMA sim GEMM + per-row top-5 (m97 structure, swizzled LDS) ----------
// grid: 1024 blocks = 64 i-tiles x 16 j-partitions; block = 256 thr (2x2 waves of 64x64)
__global__ __launch_bounds__(256, 3) void k_gemm_top5(const _Float16* __restrict__ f16,
                                                      float* __restrict__ toppart) {
  __shared__ float Csm[64 * 129];          // 33,024 B; epilogue C half-tile, stride 129 (bank = row+col)
  _Float16* Asm = (_Float16*)Csm;          // staging alias: 128 rows x 8 granules x 8 halfs = 16 KB
  _Float16* Bsm = Asm + 128 * 64;          // next 16 KB (total 32 KB <= 33 KB)

  int t = threadIdx.x;
  int w = t >> 6, lane = t & 63;
  int wr = w >> 1, wc = w & 1;
  int l15 = lane & 15, l4 = lane >> 4;
  int bi = blockIdx.x >> 4;
  int part = blockIdx.x & 15;

  float t5a[5], t5b[5];
#pragma unroll
  for (int k = 0; k < 5; k++) { t5a[k] = NEGINF; t5b[k] = NEGINF; }

  int srow = t & 63;   // scan row within 64-row phase (lane==srow within wave -> conflict-free)
  int sq = t >> 6;     // column quarter (32 cols)
  int growA = bi * 128 + srow;
  int growB = growA + 64;

  // fragment-read swizzle factors (granule = 8 halfs = 16 B; unit = row*8 + (cko ^ (row&7)))
  int swzA = l15 & 7;  // row&7 for A-fragment rows (wr*64+ti*16+l15)
  int swzB = l15 & 7;  // same for B

  for (int jt = 0; jt < JT_PER; jt++) {
    int jbase = (part * JT_PER + jt) * 128;
    f32x4 acc[4][4] = {};

    for (int kc = 0; kc < 8; kc++) {
      int k0 = kc * 64;
      __syncthreads();  // prev consumers (MFMA reads / epilogue scan) done before restage
#pragma unroll
      for (int p = 0; p < 4; p++) {
        int u = p * 256 + t;          // LDS unit index, lane-linear (forced by global_load_lds)
        int row = u >> 3;             // 0..127
        int cko = (u & 7) ^ (row & 7);  // XOR-swizzled source granule
        const _Float16* sA = f16 + (size_t)(bi * 128 + row) * DIM + k0 + cko * 8;
        const _Float16* sB = f16 + (size_t)(jbase + row) * DIM + k0 + cko * 8;
        GLOAD16(sA, Asm + u * 8);
        GLOAD16(sB, Bsm + u * 8);
      }
      __syncthreads();  // vmcnt drained by barrier
#pragma unroll
      for (int s = 0; s < 2; s++) {
        half8 af[4], bf[4];
#pragma unroll
        for (int ti = 0; ti < 4; ti++) {
          int row = wr * 64 + ti * 16 + l15;
          af[ti] = *(const half8*)(Asm + (row * 8 + ((s * 4 + l4) ^ swzA)) * 8);
        }
#pragma unroll
        for (int tj = 0; tj < 4; tj++) {
          int row = wc * 64 + tj * 16 + l15;
          bf[tj] = *(const half8*)(Bsm + (row * 8 + ((s * 4 + l4) ^ swzB)) * 8);
        }
#pragma unroll
        for (int ti = 0; ti < 4; ti++)
#pragma unroll
          for (int tj = 0; tj < 4; tj++)
            acc[ti][tj] = __builtin_amdgcn_mfma_f32_16x16x32_f16(af[ti], bf[tj], acc[ti][tj], 0, 0, 0);
      }
    }

    // epilogue: two 64-row phases so LDS stays at 33 KB
    auto dump = [&]() {
#pragma unroll
      for (int ti = 0; ti < 4; ti++) {
        int r0 = ti * 16 + l4 * 4;
#pragma unroll
        for (int tj = 0; tj < 4; tj++) {
          int c = wc * 64 + tj * 16 + l15;
#pragma unroll
          for (int reg = 0; reg < 4; reg++)
            Csm[(r0 + reg) * 129 + c] = acc[ti][tj][reg];
        }
      }
    };
    auto scan = [&](float (&t5)[5], int grow) {
      const float* rowp = Csm + srow * 129 + sq * 32;
      int gc0 = jbase + sq * 32;
#pragma unroll
      for (int it = 0; it < 8; it++) {
        float v0 = rowp[it * 4 + 0], v1 = rowp[it * 4 + 1];
        float v2 = rowp[it * 4 + 2], v3 = rowp[it * 4 + 3];
        float mx = fmaxf(fmaxf(v0, v1), fmaxf(v2, v3));
        if (mx > t5[4]) {  // rare after warm-up
          int gc = gc0 + it * 4;
          if (v0 > t5[4] && gc + 0 != grow) ins5(t5, v0);
          if (v1 > t5[4] && gc + 1 != grow) ins5(t5, v1);
          if (v2 > t5[4] && gc + 2 != grow) ins5(t5, v2);
          if (v3 > t5[4] && gc + 3 != grow) ins5(t5, v3);
        }
      }
    };

    __syncthreads();               // all MFMA LDS reads done before C overwrite
    if (wr == 0) dump();           // rows 0..63
    __syncthreads();
    scan(t5a, growA);
    __syncthreads();
    if (wr == 1) dump();           // rows 64..127
    __syncthreads();
    scan(t5b, growB);
  }

  // merge the 4 column-quarters per row inside the block (via Csm), then one
  // sorted top-5 list per (part,row): toppart[part][global_row][8]
  __syncthreads();
  {
    float* slotA = Csm + (size_t)(sq * 128 + srow) * 8;        // 4*128*8 floats = 16 KB
    float* slotB = Csm + (size_t)(sq * 128 + 64 + srow) * 8;
#pragma unroll
    for (int k = 0; k < 5; k++) { slotA[k] = t5a[k]; slotB[k] = t5b[k]; }
  }
  __syncthreads();
  if (t < 128) {
    float t5[5];
#pragma unroll
    for (int k = 0; k < 5; k++) t5[k] = NEGINF;
#pragma unroll
    for (int q = 0; q < 4; q++) {
      const float* s5 = Csm + (size_t)(q * 128 + t) * 8;
      for (int k = 0; k < 5; k++) {   // sorted desc -> early break
        float v = s5[k];
        if (!(v > t5[4])) break;
        ins5(t5, v);
      }
    }
    float* d = toppart + ((size_t)part * BN + (size_t)(bi * 128 + t)) * 8;
#pragma unroll
    for (int k = 0; k < 5; k++) d[k] = t5[k];
  }
}

// ---------- 4. merge 16 parts of sorted top-5 lists per row; global max via atomicMax ----------
__global__ __launch_bounds__(256) void k_merge(const float* __restrict__ toppart,
                                               float* __restrict__ merged,
                                               unsigned* __restrict__ cells) {
  __shared__ float red[256];
  int t = threadIdx.x;
  int row = blockIdx.x * 256 + t;
  float t5[5];
#pragma unroll
  for (int k = 0; k < 5; k++) t5[k] = NEGINF;
  for (int p = 0; p < NPART; p++) {
    const float* s5 = toppart + ((size_t)p * BN + row) * 8;
    for (int k = 0; k < 5; k++) {   // sorted desc -> early break
      float v = s5[k];
      if (!(v > t5[4])) break;
      ins5(t5, v);
    }
  }
  float* d = merged + (size_t)row * 8;
#pragma unroll
  for (int k = 0; k < 5; k++) d[k] = t5[k];
  // block max of per-row top1 -> device atomicMax (encoded)
  red[t] = t5[0];
  __syncthreads();
  for (int o = 128; o > 0; o >>= 1) {
    if (t < o) red[t] = fmaxf(red[t], red[t + o]);
    __syncthreads();
  }
  if (t == 0) atomicMax(&cells[0], encf(red[0]));
}

// ---------- 5. per-row loss, partial sums via atomicAdd (32 blocks) ----------
__global__ __launch_bounds__(256) void k_final(const float* __restrict__ merged,
                                               const float4* __restrict__ stats,
                                               unsigned* __restrict__ cells) {
  __shared__ float red[256];
  int t = threadIdx.x;
  int row = blockIdx.x * 256 + t;
  float Mg = decf(cells[0]);
  const float* m5 = merged + (size_t)row * 8;
  float h = 0.f;
#pragma unroll
  for (int k = 0; k < 5; k++) h += expf((m5[k] - Mg) / TEMP);
  float4 st = stats[row];  // m, s, psum, cnt
  float v = 0.f;
  if (st.w > 0.f) v = logf(st.y + h) - (st.z / st.w) / TEMP;
  red[t] = v;
  __syncthreads();
  for (int o = 128; o > 0; o >>= 1) {
    if (t < o) red[t] += red[t + o];
    __syncthreads();
  }
  if (t == 0) atomicAdd((float*)cells + 1, red[0]);
}

// ---------- 6. scale to mean ----------
__global__ void k_out(const unsigned* __restrict__ cells, float* __restrict__ out) {
  out[0] = ((const float*)cells)[1] * (1.0f / (float)BN);
}

extern "C" void kernel_launch(void* const* d_in, const int* in_sizes, int n_in,
                              void* d_out, int out_size, void* d_ws, size_t ws_size,
                              hipStream_t stream) {
  const float* feat = (const float*)d_in[0];
  const int* idx = (const int*)d_in[1];
  float* out = (float*)d_out;
  char* ws = (char*)d_ws;

  _Float16* f16 = (_Float16*)ws;                                   // 8 MB
  float* toppart = (float*)(ws + (size_t)8 * 1024 * 1024);         // 4 MB (16 x 8192 x 8 f32)
  float* merged = (float*)(ws + (size_t)12 * 1024 * 1024);         // 256 KB
  float4* stats = (float4*)(ws + (size_t)12 * 1024 * 1024 + 262144);  // 128 KB
  unsigned* cells = (unsigned*)(ws + (size_t)12 * 1024 * 1024 + 262144 + 131072);  // 8 B

  k_normalize<<<dim3(BN / 4), dim3(256), 0, stream>>>(feat, f16, cells);
  k_posstats<<<dim3(BN / 4), dim3(256), 0, stream>>>(f16, idx, stats);
  k_gemm_top5<<<dim3((BN / 128) * NPART), dim3(256), 0, stream>>>(f16, toppart);
  k_merge<<<dim3(BN / 256), dim3(256), 0, stream>>>(toppart, merged, cells);
  k_final<<<dim3(BN / 256), dim3(256), 0, stream>>>(merged, stats, cells);
  k_out<<<dim3(1), dim3(1), 0, stream>>>(cells, out);
}

// Round 3
// 230.145 us; speedup vs baseline: 1.3856x; 1.0769x over previous
//
#include <hip/hip_runtime.h>

#define BN 8192
#define DIM 512
#define TEMP 0.07f
#define NPART 12
#define NEGINF (-__builtin_inff())

typedef _Float16 half8 __attribute__((ext_vector_type(8)));
typedef float f32x4 __attribute__((ext_vector_type(4)));

// async 16B global->LDS (wave-uniform base + lane*16 on the LDS side)
#define GLOAD16(gp, lp) __builtin_amdgcn_global_load_lds( \
    (__attribute__((address_space(1))) const void*)(gp),  \
    (__attribute__((address_space(3))) void*)(lp), 16, 0, 0)

__device__ __forceinline__ void ins5(float t5[5], float v) {
#pragma unroll
  for (int k = 0; k < 5; k++) {
    float old = t5[k];
    bool gt = v > old;
    t5[k] = gt ? v : old;
    v = gt ? old : v;
  }
}

// guarded LSE-merge of (m,s) with (mp,sp); s-terms are sums of exp((x-m)/TEMP)
__device__ __forceinline__ void lse_merge(float& m, float& s, float mp, float sp) {
  if (mp > m) {
    s = s * expf((m - mp) / TEMP) + sp;  // m=-inf -> exp(-inf)=0, s was 0
    m = mp;
  } else if (sp > 0.f) {                 // sp==0 iff empty partial (mp=-inf)
    s += sp * expf((mp - m) / TEMP);
  }
}

// monotone float<->uint encoding for atomicMax on signed floats
__device__ __forceinline__ unsigned encf(float x) {
  unsigned u = __float_as_uint(x);
  return (u >> 31) ? ~u : (u | 0x80000000u);
}
__device__ __forceinline__ float decf(unsigned e) {
  unsigned u = (e & 0x80000000u) ? (e & 0x7FFFFFFFu) : ~e;
  return __uint_as_float(u);
}

// ---------- 1. L2-normalize fp32 rows -> fp16 matrix (one wave per row) ----------
__global__ __launch_bounds__(256) void k_normalize(const float* __restrict__ feat,
                                                   _Float16* __restrict__ f16,
                                                   unsigned* __restrict__ cells) {
  if (blockIdx.x == 0 && threadIdx.x == 0) {
    cells[0] = encf(NEGINF);        // global-max accumulator (encoded)
    ((float*)cells)[1] = 0.0f;      // loss-sum accumulator
  }
  int gid = blockIdx.x * 256 + threadIdx.x;
  int row = gid >> 6, lane = gid & 63;
  const float4* rp = (const float4*)(feat + (size_t)row * DIM);
  float4 v0 = rp[lane * 2];
  float4 v1 = rp[lane * 2 + 1];
  float ss = v0.x * v0.x + v0.y * v0.y + v0.z * v0.z + v0.w * v0.w +
             v1.x * v1.x + v1.y * v1.y + v1.z * v1.z + v1.w * v1.w;
#pragma unroll
  for (int m = 1; m < 64; m <<= 1) ss += __shfl_xor(ss, m, 64);
  float r = 1.0f / fmaxf(sqrtf(ss), 1e-12f);
  half8 o;
  o[0] = (_Float16)(v0.x * r); o[1] = (_Float16)(v0.y * r);
  o[2] = (_Float16)(v0.z * r); o[3] = (_Float16)(v0.w * r);
  o[4] = (_Float16)(v1.x * r); o[5] = (_Float16)(v1.y * r);
  o[6] = (_Float16)(v1.z * r); o[7] = (_Float16)(v1.w * r);
  ((half8*)(f16 + (size_t)row * DIM))[lane] = o;
}

// ---------- 2. fused fp16-MFMA sim GEMM + per-row top-5 + positive stats ----------
// grid: 768 blocks = 64 i-tiles x 12 parts (parts 0-3: 6 j-tiles, 4-11: 5) = 3/CU exact.
// per (part,row) output: t5[5], m, s, psum, cnt  (stride 16 floats)
__global__ __launch_bounds__(256, 3) void k_gemm_top5(const _Float16* __restrict__ f16,
                                                      const int* __restrict__ idx,
                                                      float* __restrict__ toppart) {
  __shared__ float Csm[64 * 129];          // 33,024 B; C half-tile, stride 129 (bank = row+col, 2-way max)
  _Float16* Asm = (_Float16*)Csm;          // staging alias: 128 rows x 8 granules x 8 halfs = 16 KB
  _Float16* Bsm = Asm + 128 * 64;          // next 16 KB

  int t = threadIdx.x;
  int w = t >> 6, lane = t & 63;
  int wr = w >> 1, wc = w & 1;
  int l15 = lane & 15, l4 = lane >> 4;
  int b = blockIdx.x;
  int part = b % NPART;
  int bi = b / NPART;
  int startp = part < 4 ? part * 6 : 24 + (part - 4) * 5;
  int cntp = part < 4 ? 6 : 5;

  int srow = t & 63;   // scan row within 64-row phase
  int sq = t >> 6;     // column quarter (32 cols)
  int growA = bi * 128 + srow;
  int growB = growA + 64;
  int myA = idx[growA], myB = idx[growB];

  float t5a[5], t5b[5];
  float mA = NEGINF, sA = 0.f, psA = 0.f, cnA = 0.f;
  float mB = NEGINF, sB = 0.f, psB = 0.f, cnB = 0.f;
#pragma unroll
  for (int k = 0; k < 5; k++) { t5a[k] = NEGINF; t5b[k] = NEGINF; }

  int swz = l15 & 7;   // fragment-read XOR swizzle (matches staging granule permutation)

  for (int jj = 0; jj < cntp; jj++) {
    int jbase = (startp + jj) * 128;
    f32x4 acc[4][4] = {};

    for (int kc = 0; kc < 8; kc++) {
      int k0 = kc * 64;
      __syncthreads();  // prev consumers done before restage
#pragma unroll
      for (int p = 0; p < 4; p++) {
        int u = p * 256 + t;            // LDS unit index, lane-linear (forced by global_load_lds)
        int row = u >> 3;               // 0..127
        int cko = (u & 7) ^ (row & 7);  // XOR-swizzled source granule
        const _Float16* sAp = f16 + (size_t)(bi * 128 + row) * DIM + k0 + cko * 8;
        const _Float16* sBp = f16 + (size_t)(jbase + row) * DIM + k0 + cko * 8;
        GLOAD16(sAp, Asm + u * 8);
        GLOAD16(sBp, Bsm + u * 8);
      }
      __syncthreads();  // vmcnt drained by barrier
#pragma unroll
      for (int s = 0; s < 2; s++) {
        half8 af[4], bf[4];
#pragma unroll
        for (int ti = 0; ti < 4; ti++) {
          int row = wr * 64 + ti * 16 + l15;
          af[ti] = *(const half8*)(Asm + (row * 8 + ((s * 4 + l4) ^ swz)) * 8);
        }
#pragma unroll
        for (int tj = 0; tj < 4; tj++) {
          int row = wc * 64 + tj * 16 + l15;
          bf[tj] = *(const half8*)(Bsm + (row * 8 + ((s * 4 + l4) ^ swz)) * 8);
        }
#pragma unroll
        for (int ti = 0; ti < 4; ti++)
#pragma unroll
          for (int tj = 0; tj < 4; tj++)
            acc[ti][tj] = __builtin_amdgcn_mfma_f32_16x16x32_f16(af[ti], bf[tj], acc[ti][tj], 0, 0, 0);
      }
    }

    // per-jt match masks: bit i of mMA/mMB = (idx[jbase+sq*32+i] == my{A,B})
    unsigned mMA = 0, mMB = 0;
    {
      const int4* ip = (const int4*)(idx + jbase + sq * 32);
#pragma unroll
      for (int q = 0; q < 8; q++) {
        int4 cv = ip[q];
        mMA |= ((unsigned)(cv.x == myA) << (q * 4)) | ((unsigned)(cv.y == myA) << (q * 4 + 1)) |
               ((unsigned)(cv.z == myA) << (q * 4 + 2)) | ((unsigned)(cv.w == myA) << (q * 4 + 3));
        mMB |= ((unsigned)(cv.x == myB) << (q * 4)) | ((unsigned)(cv.y == myB) << (q * 4 + 1)) |
               ((unsigned)(cv.z == myB) << (q * 4 + 2)) | ((unsigned)(cv.w == myB) << (q * 4 + 3));
      }
    }

    auto dump = [&]() {
#pragma unroll
      for (int ti = 0; ti < 4; ti++) {
        int r0 = ti * 16 + l4 * 4;
#pragma unroll
        for (int tj = 0; tj < 4; tj++) {
          int c = wc * 64 + tj * 16 + l15;
#pragma unroll
          for (int reg = 0; reg < 4; reg++)
            Csm[(r0 + reg) * 129 + c] = acc[ti][tj][reg];
        }
      }
    };
    auto scan = [&](float (&t5)[5], float& m, float& s, float& ps, float& cn,
                    int grow, unsigned match) {
      const float* rowp = Csm + srow * 129 + sq * 32;
      int gc0 = jbase + sq * 32;
#pragma unroll
      for (int it = 0; it < 8; it++) {
        float v0 = rowp[it * 4 + 0], v1 = rowp[it * 4 + 1];
        float v2 = rowp[it * 4 + 2], v3 = rowp[it * 4 + 3];
        unsigned m4 = (match >> (it * 4)) & 0xFu;
        float mx = fmaxf(fmaxf(v0, v1), fmaxf(v2, v3));
        if (mx > t5[4] || m4) {  // rare after warm-up
          int gc = gc0 + it * 4;
          float vv[4] = {v0, v1, v2, v3};
#pragma unroll
          for (int e = 0; e < 4; e++) {
            bool notself = (gc + e != grow);
            if (((m4 >> e) & 1u) && notself) {  // positive pair: online LSE + psum + cnt
              float v = vv[e];
              float nm = fmaxf(m, v);
              s = s * expf((m - nm) / TEMP) + expf((v - nm) / TEMP);
              m = nm;
              ps += v;
              cn += 1.f;
            }
            if (vv[e] > t5[4] && notself) ins5(t5, vv[e]);
          }
        }
      }
    };

    __syncthreads();               // all MFMA LDS reads done before C overwrite
    if (wr == 0) dump();           // rows 0..63
    __syncthreads();
    scan(t5a, mA, sA, psA, cnA, growA, mMA);
    __syncthreads();
    if (wr == 1) dump();           // rows 64..127
    __syncthreads();
    scan(t5b, mB, sB, psB, cnB, growB, mMB);
  }

  // merge the 4 column-quarters per row inside the block (LDS slots, stride 9 floats:
  // 9 coprime 32 -> conflict-free scalar writes), then store one record per (part,row)
  __syncthreads();
  {
    float* slotA = Csm + (size_t)(sq * 128 + srow) * 9;       // 512*9 = 4608 floats < 8256
    float* slotB = Csm + (size_t)(sq * 128 + 64 + srow) * 9;
#pragma unroll
    for (int k = 0; k < 5; k++) { slotA[k] = t5a[k]; slotB[k] = t5b[k]; }
    slotA[5] = mA; slotA[6] = sA; slotA[7] = psA; slotA[8] = cnA;
    slotB[5] = mB; slotB[6] = sB; slotB[7] = psB; slotB[8] = cnB;
  }
  __syncthreads();
  if (t < 128) {
    float t5[5];
    float m = NEGINF, s = 0.f, ps = 0.f, cn = 0.f;
#pragma unroll
    for (int k = 0; k < 5; k++) t5[k] = NEGINF;
#pragma unroll
    for (int q = 0; q < 4; q++) {
      const float* s9 = Csm + (size_t)(q * 128 + t) * 9;
      for (int k = 0; k < 5; k++) {   // sorted desc -> early break
        float v = s9[k];
        if (!(v > t5[4])) break;
        ins5(t5, v);
      }
      lse_merge(m, s, s9[5], s9[6]);
      ps += s9[7];
      cn += s9[8];
    }
    float* d = toppart + ((size_t)part * BN + (size_t)(bi * 128 + t)) * 16;
#pragma unroll
    for (int k = 0; k < 5; k++) d[k] = t5[k];
    d[5] = m; d[6] = s; d[7] = ps; d[8] = cn;
  }
}

// ---------- 3. merge 12 parts per row; global max via atomicMax ----------
__global__ __launch_bounds__(256) void k_merge(const float* __restrict__ toppart,
                                               float* __restrict__ merged,
                                               unsigned* __restrict__ cells) {
  __shared__ float red[256];
  int t = threadIdx.x;
  int row = blockIdx.x * 256 + t;
  float t5[5];
  float m = NEGINF, s = 0.f, ps = 0.f, cn = 0.f;
#pragma unroll
  for (int k = 0; k < 5; k++) t5[k] = NEGINF;
  for (int p = 0; p < NPART; p++) {
    const float* s16 = toppart + ((size_t)p * BN + row) * 16;
    for (int k = 0; k < 5; k++) {   // sorted desc -> early break
      float v = s16[k];
      if (!(v > t5[4])) break;
      ins5(t5, v);
    }
    lse_merge(m, s, s16[5], s16[6]);
    ps += s16[7];
    cn += s16[8];
  }
  float* d = merged + (size_t)row * 8;
#pragma unroll
  for (int k = 0; k < 5; k++) d[k] = t5[k];
  d[5] = s; d[6] = ps; d[7] = cn;   // m no longer needed downstream
  // block max of per-row top1 -> device atomicMax (encoded)
  red[t] = t5[0];
  __syncthreads();
  for (int o = 128; o > 0; o >>= 1) {
    if (t < o) red[t] = fmaxf(red[t], red[t + o]);
    __syncthreads();
  }
  if (t == 0) atomicMax(&cells[0], encf(red[0]));
}

// ---------- 4. per-row loss, partial sums via atomicAdd (32 blocks) ----------
__global__ __launch_bounds__(256) void k_final(const float* __restrict__ merged,
                                               unsigned* __restrict__ cells) {
  __shared__ float red[256];
  int t = threadIdx.x;
  int row = blockIdx.x * 256 + t;
  float Mg = decf(cells[0]);
  const float* m8 = merged + (size_t)row * 8;
  float h = 0.f;
#pragma unroll
  for (int k = 0; k < 5; k++) h += expf((m8[k] - Mg) / TEMP);
  float s = m8[5], ps = m8[6], cn = m8[7];
  float v = 0.f;
  if (cn > 0.f) v = logf(s + h) - (ps / cn) / TEMP;
  red[t] = v;
  __syncthreads();
  for (int o = 128; o > 0; o >>= 1) {
    if (t < o) red[t] += red[t + o];
    __syncthreads();
  }
  if (t == 0) atomicAdd((float*)cells + 1, red[0]);
}

// ---------- 5. scale to mean ----------
__global__ void k_out(const unsigned* __restrict__ cells, float* __restrict__ out) {
  out[0] = ((const float*)cells)[1] * (1.0f / (float)BN);
}

extern "C" void kernel_launch(void* const* d_in, const int* in_sizes, int n_in,
                              void* d_out, int out_size, void* d_ws, size_t ws_size,
                              hipStream_t stream) {
  const float* feat = (const float*)d_in[0];
  const int* idx = (const int*)d_in[1];
  float* out = (float*)d_out;
  char* ws = (char*)d_ws;

  _Float16* f16 = (_Float16*)ws;                                   // 8 MB
  float* toppart = (float*)(ws + (size_t)8 * 1024 * 1024);         // 6 MB (12 x 8192 x 16 f32)
  float* merged = (float*)(ws + (size_t)14 * 1024 * 1024);         // 256 KB (8192 x 8 f32)
  unsigned* cells = (unsigned*)(ws + (size_t)14 * 1024 * 1024 + 262144);  // 8 B

  k_normalize<<<dim3(BN / 4), dim3(256), 0, stream>>>(feat, f16, cells);
  k_gemm_top5<<<dim3((BN / 128) * NPART), dim3(256), 0, stream>>>(f16, idx, toppart);
  k_merge<<<dim3(BN / 256), dim3(256), 0, stream>>>(toppart, merged, cells);
  k_final<<<dim3(BN / 256), dim3(256), 0, stream>>>(merged, cells);
  k_out<<<dim3(1), dim3(1), 0, stream>>>(cells, out);
}